// Round 6
// baseline (1703.637 us; speedup 1.0000x reference)
//
#include <hip/hip_runtime.h>
#include <cmath>

#define N_NODES 50000
#define N_EDGES 800000
#define F_IN 92
#define DIM 64
#define EF 50
#define NLAYER 3
#define NGRAPH 128
#define ZROWS 178   // 2*DIM + EF

// ---------------- pre FC: h = relu(x @ pre_W + pre_b) ----------------
// (round-2 config: small share of runtime, leave as-is)
__global__ __launch_bounds__(256, 3) void pre_fc(const float* __restrict__ x,
                                                 const float* __restrict__ W,
                                                 const float* __restrict__ b,
                                                 float* __restrict__ h, int N)
{
    const int lane = threadIdx.x & 63;
    const int wid  = blockIdx.x * (blockDim.x >> 6) + (threadIdx.x >> 6);
    const int nw   = gridDim.x * (blockDim.x >> 6);
    float w[F_IN];
#pragma unroll
    for (int k = 0; k < F_IN; ++k) w[k] = W[k * DIM + lane];
    const float bb = b[lane];
#pragma unroll 1
    for (int n = wid; n < N; n += nw) {
        const int nu = __builtin_amdgcn_readfirstlane(n);
        const float* xr = x + (size_t)nu * F_IN;
        float a = bb;
#pragma unroll
        for (int k = 0; k < F_IN; ++k) a = fmaf(xr[k], w[k], a);
        h[(size_t)nu * DIM + lane] = fmaxf(a, 0.f);
    }
}

// ---------------- degree + graph-node counts ----------------
__global__ __launch_bounds__(256) void deg_cnt(const int* __restrict__ ei, int E,
                                               const int* __restrict__ batch, int N,
                                               float* __restrict__ deg,
                                               float* __restrict__ cnt)
{
    const int i = blockIdx.x * blockDim.x + threadIdx.x;
    const int stride = gridDim.x * blockDim.x;
    for (int e = i; e < E; e += stride) unsafeAtomicAdd(&deg[ei[E + e]], 1.f);
    for (int n = i; n < N; n += stride) unsafeAtomicAdd(&cnt[batch[n]], 1.f);
}

// ---------------- node projections for layer l ----------------
// Pd[n] = [ h@Wf[0:64] + bf | h@Ws[0:64] + bs ]   (dst/i, biases folded)
// Ps[n] = [ h@Wf[64:128]    | h@Ws[64:128]     ]  (src/j)
// (round-2 config)
__global__ __launch_bounds__(256, 2) void node_proj(const float* __restrict__ h,
                                                    const float* __restrict__ Wfl,
                                                    const float* __restrict__ Wsl,
                                                    const float* __restrict__ bf,
                                                    const float* __restrict__ bs,
                                                    float* __restrict__ Pd,
                                                    float* __restrict__ Ps, int N)
{
    const int lane = threadIdx.x & 63;
    const int wid  = blockIdx.x * (blockDim.x >> 6) + (threadIdx.x >> 6);
    const int nw   = gridDim.x * (blockDim.x >> 6);
    const int half = wid & 1;  // 0 -> Pd, 1 -> Ps
    const float* wfb = Wfl + (half ? DIM * DIM : 0);
    const float* wsb = Wsl + (half ? DIM * DIM : 0);
    float wf[DIM], ws[DIM];
#pragma unroll
    for (int k = 0; k < DIM; ++k) { wf[k] = wfb[k * DIM + lane]; ws[k] = wsb[k * DIM + lane]; }
    const float b0 = half ? 0.f : bf[lane];
    const float b1 = half ? 0.f : bs[lane];
    float* P = half ? Ps : Pd;
#pragma unroll 1
    for (int n = (wid >> 1); n < N; n += (nw >> 1)) {
        const int nu = __builtin_amdgcn_readfirstlane(n);
        const float* hr = h + (size_t)nu * DIM;
        float a0 = b0, a1 = b1;
#pragma unroll
        for (int k = 0; k < DIM; ++k) {
            const float v = hr[k];
            a0 = fmaf(v, wf[k], a0);
            a1 = fmaf(v, ws[k], a1);
        }
        P[(size_t)nu * 128 + lane]      = a0;
        P[(size_t)nu * 128 + 64 + lane] = a1;
    }
}

// ---------------- fused edge kernel: eattr projection (SGPR weights,
// lane=edge) -> LDS transpose -> gate+scatter (lane=dim) ----------------
// One block = one tile of 64 edges.
// Phase A: wave wv computes cols [wv*32, wv*32+32) of the 128-dim eattr
//   projection for all 64 edges. Weight operand W[k*64+c] is wave-uniform
//   -> scalar loads (no VGPR pressure). acc[32] per thread.
// Phase B: wave wv processes edges [wv*16, wv*16+16): lane=dim, reads the
//   projection pair from the padded LDS tile, gathers Pd/Ps (coalesced),
//   gates, atomically accumulates into agg[dst].
#define EA_PAD 51   // 64x51 eattr stage: bank (e*51+k)%32, 51 odd -> conflict-free
#define TP_PAD 129  // 64x129 transpose tile: odd pad -> conflict-free both phases
__global__ __launch_bounds__(256) void edge_fused(const int* __restrict__ ei,
                                                  const float* __restrict__ eattr,
                                                  const float* __restrict__ Pd,
                                                  const float* __restrict__ Ps,
                                                  const float* __restrict__ WfE,
                                                  const float* __restrict__ WsE,
                                                  float* __restrict__ agg, int E)
{
    __shared__ float ea_lds[64 * EA_PAD];
    __shared__ float out_lds[64 * TP_PAD];

    const int tid = threadIdx.x;
    const int e0  = blockIdx.x * 64;

    // ---- stage 64 eattr rows (coalesced global read) ----
    {
        const float* src = eattr + (size_t)e0 * EF;
        for (int idx = tid; idx < 64 * EF; idx += 256) {
            const int e = idx / EF;
            const int k = idx - e * EF;
            ea_lds[e * EA_PAD + k] = src[idx];
        }
    }
    __syncthreads();

    // ---- phase A: projection, lane = edge ----
    {
        const int e  = tid & 63;
        const int wv = __builtin_amdgcn_readfirstlane(threadIdx.x >> 6);  // provably uniform
        const float* Wbase = (wv < 2) ? WfE : WsE;   // uniform pointer
        const int c0 = (wv & 1) * 32;                // uniform col offset within the 64-col block
        const int cb = wv * 32;                      // output col base in [0,128)

        float acc[32];
#pragma unroll
        for (int j = 0; j < 32; ++j) acc[j] = 0.f;

        const float* ear = ea_lds + e * EA_PAD;
#pragma unroll 1
        for (int k = 0; k < EF; ++k) {
            const float eak = ear[k];                 // ds_read, conflict-free
            const float* wr = Wbase + k * DIM + c0;   // uniform -> s_load
#pragma unroll
            for (int j = 0; j < 32; ++j) acc[j] = fmaf(eak, wr[j], acc[j]);
        }
        float* orow = out_lds + e * TP_PAD + cb;
#pragma unroll
        for (int j = 0; j < 32; ++j) orow[j] = acc[j];
    }
    __syncthreads();

    // ---- phase B: gate + scatter, lane = dim ----
    {
        const int lane = tid & 63;
        const int wv   = __builtin_amdgcn_readfirstlane(threadIdx.x >> 6);
#pragma unroll 1
        for (int i = 0; i < 16; ++i) {
            const int el = wv * 16 + i;          // uniform
            const int eg = e0 + el;
            const int s  = ei[eg];               // uniform -> s_load
            const int d  = ei[E + eg];
            const float pf = out_lds[el * TP_PAD + lane];
            const float psv = out_lds[el * TP_PAD + 64 + lane];
            const float* pdr = Pd + (size_t)d * 128;
            const float* psr = Ps + (size_t)s * 128;
            const float zf = pf  + pdr[lane]      + psr[lane];
            const float zs = psv + pdr[64 + lane] + psr[64 + lane];
            const float sig = 1.f / (1.f + __expf(-zf));
            const float sp  = fmaxf(zs, 0.f) + __logf(1.f + __expf(-fabsf(zs)));
            unsafeAtomicAdd(&agg[(size_t)d * DIM + lane], sig * sp);
        }
    }
}

// ---------------- node update: h = BN(h + agg/deg) ----------------
__global__ __launch_bounds__(256) void node_update(float* __restrict__ h,
                                                   const float* __restrict__ agg,
                                                   const float* __restrict__ deg,
                                                   const float* __restrict__ gamma,
                                                   const float* __restrict__ beta,
                                                   const float* __restrict__ mean,
                                                   const float* __restrict__ var, int N)
{
    const int lane = threadIdx.x & 63;
    const float g  = gamma[lane];
    const float bt = beta[lane];
    const float mn = mean[lane];
    const float iv = rsqrtf(var[lane] + 1e-5f);
    const int idx = blockIdx.x * blockDim.x + threadIdx.x;
    const int stride = gridDim.x * blockDim.x;  // multiple of 64
    const int total = N * DIM;
    for (int i = idx; i < total; i += stride) {
        const int n = i >> 6;
        const float inv = 1.f / fmaxf(deg[n], 1.f);
        const float v = h[i] + agg[i] * inv;
        h[i] = fmaf(g, (v - mn) * iv, bt);
    }
}

// ---------------- global mean pool (sum part) ----------------
__global__ __launch_bounds__(256) void pool_sum(const float* __restrict__ h,
                                                const int* __restrict__ batch,
                                                float* __restrict__ gsum, int N)
{
    const int lane = threadIdx.x & 63;
    const int wid  = blockIdx.x * (blockDim.x >> 6) + (threadIdx.x >> 6);
    const int nw   = gridDim.x * (blockDim.x >> 6);
    for (int n = wid; n < N; n += nw) {
        const int nu = __builtin_amdgcn_readfirstlane(n);
        const int b = batch[nu];
        unsafeAtomicAdd(&gsum[(size_t)b * DIM + lane], h[(size_t)nu * DIM + lane]);
    }
}

// ---------------- head: g=relu(mean@postW+postb); out = g@outW+outb ----------------
__global__ __launch_bounds__(64) void head(const float* __restrict__ gsum,
                                           const float* __restrict__ cnt,
                                           const float* __restrict__ postW,
                                           const float* __restrict__ postb,
                                           const float* __restrict__ outW,
                                           const float* __restrict__ outb,
                                           float* __restrict__ out)
{
    const int gi = blockIdx.x;
    const int lane = threadIdx.x;
    const float inv = 1.f / fmaxf(cnt[gi], 1.f);
    const float gval = gsum[(size_t)gi * DIM + lane] * inv;
    float acc = postb[lane];
#pragma unroll
    for (int k = 0; k < DIM; ++k) acc = fmaf(__shfl(gval, k, 64), postW[k * DIM + lane], acc);
    const float t = fmaxf(acc, 0.f);
    float prod = t * outW[lane];
#pragma unroll
    for (int off = 32; off > 0; off >>= 1) prod += __shfl_down(prod, off, 64);
    if (lane == 0) out[gi] = prod + outb[0];
}

extern "C" void kernel_launch(void* const* d_in, const int* in_sizes, int n_in,
                              void* d_out, int out_size, void* d_ws, size_t ws_size,
                              hipStream_t stream)
{
    const float* x     = (const float*)d_in[0];
    const int*   ei    = (const int*)d_in[1];
    const float* eattr = (const float*)d_in[2];
    const int*   batch = (const int*)d_in[3];
    const float* preW  = (const float*)d_in[4];
    const float* preb  = (const float*)d_in[5];
    const float* Wf    = (const float*)d_in[6];
    const float* bf    = (const float*)d_in[7];
    const float* Ws    = (const float*)d_in[8];
    const float* bs    = (const float*)d_in[9];
    const float* gamma = (const float*)d_in[10];
    const float* beta  = (const float*)d_in[11];
    const float* mean  = (const float*)d_in[12];
    const float* var   = (const float*)d_in[13];
    const float* postW = (const float*)d_in[14];
    const float* postb = (const float*)d_in[15];
    const float* outW  = (const float*)d_in[16];
    const float* outb  = (const float*)d_in[17];
    float* out = (float*)d_out;

    const int N = N_NODES, E = N_EDGES, G = NGRAPH;

    char* p = (char*)d_ws;
    float* h    = (float*)p; p += (size_t)N * DIM * 4;
    float* Pd   = (float*)p; p += (size_t)N * 128 * 4;
    float* Ps   = (float*)p; p += (size_t)N * 128 * 4;
    float* agg  = (float*)p; p += (size_t)N * DIM * 4;
    float* deg  = (float*)p; p += (size_t)N * 4;
    float* gsum = (float*)p; p += (size_t)G * DIM * 4;
    float* cnt  = (float*)p; p += (size_t)G * 4;

    // zero deg + gsum + cnt (contiguous)
    hipMemsetAsync(deg, 0, ((size_t)N + G * DIM + G) * 4, stream);

    pre_fc<<<512, 256, 0, stream>>>(x, preW, preb, h, N);
    deg_cnt<<<512, 256, 0, stream>>>(ei, E, batch, N, deg, cnt);

    for (int l = 0; l < NLAYER; ++l) {
        const float* Wfl = Wf + (size_t)l * ZROWS * DIM;
        const float* Wsl = Ws + (size_t)l * ZROWS * DIM;
        hipMemsetAsync(agg, 0, (size_t)N * DIM * 4, stream);
        node_proj<<<512, 256, 0, stream>>>(h, Wfl, Wsl, bf + l * DIM, bs + l * DIM, Pd, Ps, N);
        edge_fused<<<E / 64, 256, 0, stream>>>(ei, eattr, Pd, Ps,
                                               Wfl + 2 * DIM * DIM, Wsl + 2 * DIM * DIM, agg, E);
        node_update<<<1024, 256, 0, stream>>>(h, agg, deg, gamma + l * DIM, beta + l * DIM,
                                              mean + l * DIM, var + l * DIM, N);
    }

    pool_sum<<<512, 256, 0, stream>>>(h, batch, gsum, N);
    head<<<G, 64, 0, stream>>>(gsum, cnt, postW, postb, outW, outb, out);
}

// Round 7
// 1056.129 us; speedup vs baseline: 1.6131x; 1.6131x over previous
//
#include <hip/hip_runtime.h>
#include <cmath>

#define N_NODES 50000
#define N_EDGES 800000
#define F_IN 92
#define DIM 64
#define EF 50
#define NLAYER 3
#define NGRAPH 128
#define ZROWS 178   // 2*DIM + EF

// ---------------- pre FC: h = relu(x @ pre_W + pre_b) ----------------
__global__ __launch_bounds__(256, 3) void pre_fc(const float* __restrict__ x,
                                                 const float* __restrict__ W,
                                                 const float* __restrict__ b,
                                                 float* __restrict__ h, int N)
{
    const int lane = threadIdx.x & 63;
    const int wid  = blockIdx.x * (blockDim.x >> 6) + (threadIdx.x >> 6);
    const int nw   = gridDim.x * (blockDim.x >> 6);
    float w[F_IN];
#pragma unroll
    for (int k = 0; k < F_IN; ++k) w[k] = W[k * DIM + lane];
    const float bb = b[lane];
#pragma unroll 1
    for (int n = wid; n < N; n += nw) {
        const int nu = __builtin_amdgcn_readfirstlane(n);
        const float* xr = x + (size_t)nu * F_IN;
        float a = bb;
#pragma unroll
        for (int k = 0; k < F_IN; ++k) a = fmaf(xr[k], w[k], a);
        h[(size_t)nu * DIM + lane] = fmaxf(a, 0.f);
    }
}

// ---------------- degree + graph-node counts ----------------
__global__ __launch_bounds__(256) void deg_cnt(const int* __restrict__ ei, int E,
                                               const int* __restrict__ batch, int N,
                                               float* __restrict__ deg,
                                               float* __restrict__ cnt)
{
    const int i = blockIdx.x * blockDim.x + threadIdx.x;
    const int stride = gridDim.x * blockDim.x;
    for (int e = i; e < E; e += stride) unsafeAtomicAdd(&deg[ei[E + e]], 1.f);
    for (int n = i; n < N; n += stride) unsafeAtomicAdd(&cnt[batch[n]], 1.f);
}

// ---------------- node projections for layer l ----------------
// Pd[n] = [ h@Wf[0:64] + bf | h@Ws[0:64] + bs ]   (dst/i, biases folded)
// Ps[n] = [ h@Wf[64:128]    | h@Ws[64:128]     ]  (src/j)
__global__ __launch_bounds__(256, 2) void node_proj(const float* __restrict__ h,
                                                    const float* __restrict__ Wfl,
                                                    const float* __restrict__ Wsl,
                                                    const float* __restrict__ bf,
                                                    const float* __restrict__ bs,
                                                    float* __restrict__ Pd,
                                                    float* __restrict__ Ps, int N)
{
    const int lane = threadIdx.x & 63;
    const int wid  = blockIdx.x * (blockDim.x >> 6) + (threadIdx.x >> 6);
    const int nw   = gridDim.x * (blockDim.x >> 6);
    const int half = wid & 1;  // 0 -> Pd, 1 -> Ps
    const float* wfb = Wfl + (half ? DIM * DIM : 0);
    const float* wsb = Wsl + (half ? DIM * DIM : 0);
    float wf[DIM], ws[DIM];
#pragma unroll
    for (int k = 0; k < DIM; ++k) { wf[k] = wfb[k * DIM + lane]; ws[k] = wsb[k * DIM + lane]; }
    const float b0 = half ? 0.f : bf[lane];
    const float b1 = half ? 0.f : bs[lane];
    float* P = half ? Ps : Pd;
#pragma unroll 1
    for (int n = (wid >> 1); n < N; n += (nw >> 1)) {
        const int nu = __builtin_amdgcn_readfirstlane(n);
        const float* hr = h + (size_t)nu * DIM;
        float a0 = b0, a1 = b1;
#pragma unroll
        for (int k = 0; k < DIM; ++k) {
            const float v = hr[k];
            a0 = fmaf(v, wf[k], a0);
            a1 = fmaf(v, ws[k], a1);
        }
        P[(size_t)nu * 128 + lane]      = a0;
        P[(size_t)nu * 128 + 64 + lane] = a1;
    }
}

// ---------------- fused edge kernel: eattr projection (SGPR weights,
// lane=edge) -> LDS transpose -> gate+scatter (lane=dim) ----------------
// One block = 512 threads (8 waves) = one tile of 64 edges.
// LDS 46 KB -> 3 blocks/CU -> 24 waves/CU (75% occupancy) for latency hiding.
// Phase A: wave wv computes 16 cols of the 128-dim projection for all 64
//   edges; weight operand wave-uniform -> s_load (zero VGPR pressure).
// Phase B: wave wv gates+scatters 8 edges, lane = dim, unroll 2 for MLP.
#define EA_PAD 51   // odd stride -> conflict-free by-row and by-col access
#define TP_PAD 129  // odd stride -> conflict-free write (lane=e) and read (lane=dim)
__global__ __launch_bounds__(512) void edge_fused(const int* __restrict__ ei,
                                                  const float* __restrict__ eattr,
                                                  const float* __restrict__ Pd,
                                                  const float* __restrict__ Ps,
                                                  const float* __restrict__ WfE,
                                                  const float* __restrict__ WsE,
                                                  float* __restrict__ agg, int E)
{
    __shared__ float ea_lds[64 * EA_PAD];
    __shared__ float out_lds[64 * TP_PAD];

    const int tid = threadIdx.x;
    const int e0  = blockIdx.x * 64;

    // ---- stage 64 eattr rows (coalesced global read) ----
    {
        const float* src = eattr + (size_t)e0 * EF;
        for (int idx = tid; idx < 64 * EF; idx += 512) {
            const int e = idx / EF;
            const int k = idx - e * EF;
            ea_lds[e * EA_PAD + k] = src[idx];
        }
    }
    __syncthreads();

    // ---- phase A: projection, lane = edge, 16 cols per wave ----
    {
        const int e  = tid & 63;
        const int wv = __builtin_amdgcn_readfirstlane(tid >> 6);  // 0..7, uniform
        const float* Wbase = (wv < 4) ? WfE : WsE;   // uniform pointer
        const int c0 = (wv & 3) * 16;                // uniform col offset in [0,64)
        const int cb = ((wv < 4) ? 0 : 64) + c0;     // output col base in [0,128)

        float acc[16];
#pragma unroll
        for (int j = 0; j < 16; ++j) acc[j] = 0.f;

        const float* ear = ea_lds + e * EA_PAD;
#pragma unroll 5
        for (int k = 0; k < EF; ++k) {
            const float eak = ear[k];                 // ds_read, conflict-free
            const float* wr = Wbase + k * DIM + c0;   // uniform -> s_load_dwordx16
#pragma unroll
            for (int j = 0; j < 16; ++j) acc[j] = fmaf(eak, wr[j], acc[j]);
        }
        float* orow = out_lds + e * TP_PAD + cb;
#pragma unroll
        for (int j = 0; j < 16; ++j) orow[j] = acc[j];
    }
    __syncthreads();

    // ---- phase B: gate + scatter, lane = dim, 8 edges per wave ----
    {
        const int lane = tid & 63;
        const int wv   = __builtin_amdgcn_readfirstlane(tid >> 6);
#pragma unroll 2
        for (int i = 0; i < 8; ++i) {
            const int el = wv * 8 + i;           // uniform
            const int eg = e0 + el;
            const int s  = ei[eg];               // uniform -> s_load
            const int d  = ei[E + eg];
            const float pf  = out_lds[el * TP_PAD + lane];
            const float psv = out_lds[el * TP_PAD + 64 + lane];
            const float* pdr = Pd + (size_t)d * 128;
            const float* psr = Ps + (size_t)s * 128;
            const float zf = pf  + pdr[lane]      + psr[lane];
            const float zs = psv + pdr[64 + lane] + psr[64 + lane];
            const float sig = 1.f / (1.f + __expf(-zf));
            const float sp  = fmaxf(zs, 0.f) + __logf(1.f + __expf(-fabsf(zs)));
            unsafeAtomicAdd(&agg[(size_t)d * DIM + lane], sig * sp);
        }
    }
}

// ---------------- node update: h = BN(h + agg/deg) ----------------
__global__ __launch_bounds__(256) void node_update(float* __restrict__ h,
                                                   const float* __restrict__ agg,
                                                   const float* __restrict__ deg,
                                                   const float* __restrict__ gamma,
                                                   const float* __restrict__ beta,
                                                   const float* __restrict__ mean,
                                                   const float* __restrict__ var, int N)
{
    const int lane = threadIdx.x & 63;
    const float g  = gamma[lane];
    const float bt = beta[lane];
    const float mn = mean[lane];
    const float iv = rsqrtf(var[lane] + 1e-5f);
    const int idx = blockIdx.x * blockDim.x + threadIdx.x;
    const int stride = gridDim.x * blockDim.x;  // multiple of 64
    const int total = N * DIM;
    for (int i = idx; i < total; i += stride) {
        const int n = i >> 6;
        const float inv = 1.f / fmaxf(deg[n], 1.f);
        const float v = h[i] + agg[i] * inv;
        h[i] = fmaf(g, (v - mn) * iv, bt);
    }
}

// ---------------- global mean pool (sum part) ----------------
__global__ __launch_bounds__(256) void pool_sum(const float* __restrict__ h,
                                                const int* __restrict__ batch,
                                                float* __restrict__ gsum, int N)
{
    const int lane = threadIdx.x & 63;
    const int wid  = blockIdx.x * (blockDim.x >> 6) + (threadIdx.x >> 6);
    const int nw   = gridDim.x * (blockDim.x >> 6);
    for (int n = wid; n < N; n += nw) {
        const int nu = __builtin_amdgcn_readfirstlane(n);
        const int b = batch[nu];
        unsafeAtomicAdd(&gsum[(size_t)b * DIM + lane], h[(size_t)nu * DIM + lane]);
    }
}

// ---------------- head: g=relu(mean@postW+postb); out = g@outW+outb ----------------
__global__ __launch_bounds__(64) void head(const float* __restrict__ gsum,
                                           const float* __restrict__ cnt,
                                           const float* __restrict__ postW,
                                           const float* __restrict__ postb,
                                           const float* __restrict__ outW,
                                           const float* __restrict__ outb,
                                           float* __restrict__ out)
{
    const int gi = blockIdx.x;
    const int lane = threadIdx.x;
    const float inv = 1.f / fmaxf(cnt[gi], 1.f);
    const float gval = gsum[(size_t)gi * DIM + lane] * inv;
    float acc = postb[lane];
#pragma unroll
    for (int k = 0; k < DIM; ++k) acc = fmaf(__shfl(gval, k, 64), postW[k * DIM + lane], acc);
    const float t = fmaxf(acc, 0.f);
    float prod = t * outW[lane];
#pragma unroll
    for (int off = 32; off > 0; off >>= 1) prod += __shfl_down(prod, off, 64);
    if (lane == 0) out[gi] = prod + outb[0];
}

extern "C" void kernel_launch(void* const* d_in, const int* in_sizes, int n_in,
                              void* d_out, int out_size, void* d_ws, size_t ws_size,
                              hipStream_t stream)
{
    const float* x     = (const float*)d_in[0];
    const int*   ei    = (const int*)d_in[1];
    const float* eattr = (const float*)d_in[2];
    const int*   batch = (const int*)d_in[3];
    const float* preW  = (const float*)d_in[4];
    const float* preb  = (const float*)d_in[5];
    const float* Wf    = (const float*)d_in[6];
    const float* bf    = (const float*)d_in[7];
    const float* Ws    = (const float*)d_in[8];
    const float* bs    = (const float*)d_in[9];
    const float* gamma = (const float*)d_in[10];
    const float* beta  = (const float*)d_in[11];
    const float* mean  = (const float*)d_in[12];
    const float* var   = (const float*)d_in[13];
    const float* postW = (const float*)d_in[14];
    const float* postb = (const float*)d_in[15];
    const float* outW  = (const float*)d_in[16];
    const float* outb  = (const float*)d_in[17];
    float* out = (float*)d_out;

    const int N = N_NODES, E = N_EDGES, G = NGRAPH;

    char* p = (char*)d_ws;
    float* h    = (float*)p; p += (size_t)N * DIM * 4;
    float* Pd   = (float*)p; p += (size_t)N * 128 * 4;
    float* Ps   = (float*)p; p += (size_t)N * 128 * 4;
    float* agg  = (float*)p; p += (size_t)N * DIM * 4;
    float* deg  = (float*)p; p += (size_t)N * 4;
    float* gsum = (float*)p; p += (size_t)G * DIM * 4;
    float* cnt  = (float*)p; p += (size_t)G * 4;

    // zero deg + gsum + cnt (contiguous)
    hipMemsetAsync(deg, 0, ((size_t)N + G * DIM + G) * 4, stream);

    pre_fc<<<512, 256, 0, stream>>>(x, preW, preb, h, N);
    deg_cnt<<<512, 256, 0, stream>>>(ei, E, batch, N, deg, cnt);

    for (int l = 0; l < NLAYER; ++l) {
        const float* Wfl = Wf + (size_t)l * ZROWS * DIM;
        const float* Wsl = Ws + (size_t)l * ZROWS * DIM;
        hipMemsetAsync(agg, 0, (size_t)N * DIM * 4, stream);
        node_proj<<<512, 256, 0, stream>>>(h, Wfl, Wsl, bf + l * DIM, bs + l * DIM, Pd, Ps, N);
        edge_fused<<<E / 64, 512, 0, stream>>>(ei, eattr, Pd, Ps,
                                               Wfl + 2 * DIM * DIM, Wsl + 2 * DIM * DIM, agg, E);
        node_update<<<1024, 256, 0, stream>>>(h, agg, deg, gamma + l * DIM, beta + l * DIM,
                                              mean + l * DIM, var + l * DIM, N);
    }

    pool_sum<<<512, 256, 0, stream>>>(h, batch, gsum, N);
    head<<<G, 64, 0, stream>>>(gsum, cnt, postW, postb, outW, outb, out);
}